// Round 10
// baseline (335.042 us; speedup 1.0000x reference)
//
#include <hip/hip_runtime.h>

typedef unsigned short u16;

#define M_ROWS 8192
#define N_ROWS 16384
#define KDIM   512
#define BM     256
#define BN     256                  /* n-tile rows per K-loop pass */
#define NCHUNKS 8
#define NPER   (N_ROWS / NCHUNKS)   /* 2048 */
#define TOPK   9
#define NT     (NPER / BN)          /* 8 n-tiles per block */
#define KT     (KDIM / 64)          /* 8 K-tiles (BK=64) per n-tile */
#define NTT    (NT * KT)            /* 64 tiles */
#define HSZ    8192                 /* u16 per half-buffer: 256 rows x 32 */

typedef __attribute__((ext_vector_type(8))) short bf16x8;
typedef __attribute__((ext_vector_type(4))) float f32x4;

__device__ __forceinline__ void gload_lds16(const void* g, void* l) {
  __builtin_amdgcn_global_load_lds(
      (const __attribute__((address_space(1))) void*)g,
      (__attribute__((address_space(3))) void*)l,
      16, 0, 0);
}

__device__ __forceinline__ u16 f2bf(float x) {
  union { float f; unsigned u; } c; c.f = x;
  unsigned u = c.u;
  u += 0x7fffu + ((u >> 16) & 1u);   // RNE; inputs finite randn
  return (u16)(u >> 16);
}

__device__ __forceinline__ void topk_update(float v, float* best) {
  if (v < best[TOPK - 1]) {
    #pragma unroll
    for (int i = 0; i < TOPK; ++i) {
      float b = best[i];
      best[i] = fminf(b, v);
      v = fmaxf(b, v);
    }
  }
}

// ---- Kernel 1: fp32 -> bf16 convert + fp32 row norms. nm in PLAIN order:
// 16x16x32 C-rows are consecutive (row = (lane>>4)*4 + j), epilogue reads float4.
__global__ __launch_bounds__(256) void prep_kernel(
    const float* __restrict__ fv, const float* __restrict__ mb,
    u16* __restrict__ fvb, u16* __restrict__ mbb,
    float* __restrict__ nf, float* __restrict__ nm)
{
  int idx = blockIdx.x * 4 + (threadIdx.x >> 6);   // one wave per row
  int l = threadIdx.x & 63;
  const float* src; u16* dst;
  if (idx < M_ROWS) {
    src = fv + (size_t)idx * KDIM; dst = fvb + (size_t)idx * KDIM;
  } else {
    int r = idx - M_ROWS;
    src = mb + (size_t)r * KDIM; dst = mbb + (size_t)r * KDIM;
  }
  float4 x0 = ((const float4*)src)[2 * l];
  float4 x1 = ((const float4*)src)[2 * l + 1];
  float s = x0.x * x0.x + x0.y * x0.y + x0.z * x0.z + x0.w * x0.w
          + x1.x * x1.x + x1.y * x1.y + x1.z * x1.z + x1.w * x1.w;
  uint4 o;
  o.x = (unsigned)f2bf(x0.x) | ((unsigned)f2bf(x0.y) << 16);
  o.y = (unsigned)f2bf(x0.z) | ((unsigned)f2bf(x0.w) << 16);
  o.z = (unsigned)f2bf(x1.x) | ((unsigned)f2bf(x1.y) << 16);
  o.w = (unsigned)f2bf(x1.z) | ((unsigned)f2bf(x1.w) << 16);
  ((uint4*)dst)[l] = o;
  #pragma unroll
  for (int off = 32; off > 0; off >>= 1) s += __shfl_down(s, off, 64);
  if (l == 0) {
    if (idx < M_ROWS) nf[idx] = s;
    else              nm[idx - M_ROWS] = s;
  }
}

// ---- Kernel 2: m201-style 4-phase/K-tile bf16 16x16x32 MFMA GEMM + top-9 ----
// R10: the m201 schedule ported with a lean top-k epilogue. 512 thr / 8 waves
// (wn=w>>2 n-half 128, wm=w&3 m-quarter 64); swapped operands: C[row=n][col=m],
// col = lane&15 -> per-lane 4 m-col lists best[4][9]. acc[8][4] f32x4 = 128 AGPR.
// LDS: 4 half-buffers (A=mb [256][32] 16KB + B=fv [256][32] 16KB each) = 128 KB.
// Per K-tile (BK64) 4 phases, each {ds_reads || 2 gloads -> bar -> lgkm0 ->
// sched_bar -> prio1 16 MFMA prio0 -> [vmcnt(4) on ph1/ph3] -> bar}; 8 loads in
// flight steady-state, never drained mid-loop (T3+T4+T5). Reads:MFMA cycles per
// K-tile/wave = 24x12 : 64x4.85 = 288:310 -> first structure where MFMA >= LDS.
// R1's spill eliminated: plain-order nm (no perm regs), 4 lists, short frag
// liveness. acc128+frags32+best36+T4+addr~20 = ~220 < 256 (launch_bounds 512,2).
// Swizzle (R3-proven, 32-bf16 rows): chunk c of row r at c^((r>>1)&3); staging
// pre-swizzles per-lane source chunk ((l&3)^((l>>3)&3)); reads XOR the chunk.
__global__ __launch_bounds__(512, 2) void gemm_topk_kernel(
    const u16* __restrict__ fvb, const u16* __restrict__ mbb,
    const float* __restrict__ nm, float* __restrict__ partial)
{
  extern __shared__ __align__(16) u16 sm[];
  u16* const Ah = sm;               // 4 x [256][32] mb half-tiles (64 KB)
  u16* const Bh = sm + 4 * HSZ;     // 4 x [256][32] fv half-tiles (64 KB)

  const int t   = threadIdx.x;
  const int l   = t & 63;
  const int w   = t >> 6;          // wave 0..7
  const int wn  = w >> 2;          // n-half (0..1): 128 n-rows
  const int wm  = w & 3;           // m-quarter (0..3): 64 m-cols
  const int r16 = l & 15;
  const int g   = l >> 4;          // k-octet group / C-row group

  const int m0    = blockIdx.x * BM;
  const int ncoff = blockIdx.y * NPER;

  // staging: lane covers row l>>2, chunk l&3 (source chunk pre-swizzled)
  const int srow = l >> 2;
  const int sc8  = ((l & 3) ^ ((l >> 3) & 3)) * 8;
  // frag reads: row base + r16, k-octet g, swizzled chunk
  const int ch8  = (g ^ ((r16 >> 1) & 3)) * 8;
  const int aoff = (wn * 128 + r16) * 32 + ch8;   // into A half (u16)
  const int boff = (wm * 64 + r16) * 32 + ch8;    // into B half (u16)

  // per-lane source row offsets (uniform parts added per stage)
  const u16* bSrcF = fvb + (size_t)(m0 + w * 32 + srow) * KDIM + sc8;
  const size_t aRow = (size_t)(w * 32 + srow) * KDIM + sc8;

#define STAGE_A_H(h_) do {                                                    \
    const int th_ = (h_) >> 1;                                                \
    const size_t ko_ = (size_t)((th_ & 7) * 64 + ((h_) & 1) * 32);            \
    const u16* s_ = mbb + (size_t)(ncoff + (th_ >> 3) * BN) * KDIM + aRow + ko_; \
    u16* d_ = Ah + ((h_) & 3) * HSZ + (w * 32) * 32;                          \
    gload_lds16(s_,             d_);                                          \
    gload_lds16(s_ + 16 * KDIM, d_ + 512);                                    \
  } while (0)
#define STAGE_B_H(h_) do {                                                    \
    const int th_ = (h_) >> 1;                                                \
    const size_t ko_ = (size_t)((th_ & 7) * 64 + ((h_) & 1) * 32);            \
    const u16* s_ = bSrcF + ko_;                                              \
    u16* d_ = Bh + ((h_) & 3) * HSZ + (w * 32) * 32;                          \
    gload_lds16(s_,             d_);                                          \
    gload_lds16(s_ + 16 * KDIM, d_ + 512);                                    \
  } while (0)

#define MFMA4(AF, NF)                                                          \
  acc[NF][0] = __builtin_amdgcn_mfma_f32_16x16x32_bf16(AF, b0, acc[NF][0], 0, 0, 0); \
  acc[NF][1] = __builtin_amdgcn_mfma_f32_16x16x32_bf16(AF, b1, acc[NF][1], 0, 0, 0); \
  acc[NF][2] = __builtin_amdgcn_mfma_f32_16x16x32_bf16(AF, b2, acc[NF][2], 0, 0, 0); \
  acc[NF][3] = __builtin_amdgcn_mfma_f32_16x16x32_bf16(AF, b3, acc[NF][3], 0, 0, 0);

  float best[4][TOPK];
  float T[4];
  #pragma unroll
  for (int mf = 0; mf < 4; ++mf) {
    T[mf] = 3.4e38f;
    #pragma unroll
    for (int q = 0; q < TOPK; ++q) best[mf][q] = 3.4e38f;
  }

  f32x4 acc[8][4];

  // prologue: halves 0,1 in flight (8 loads), half 0 resident
  STAGE_A_H(0); STAGE_B_H(0);
  STAGE_A_H(1); STAGE_B_H(1);
  asm volatile("s_waitcnt vmcnt(4)" ::: "memory");
  __builtin_amdgcn_s_barrier();

  for (int tt = 0; tt < NTT; ++tt) {
    if ((tt & 7) == 0) {
      #pragma unroll
      for (int nf = 0; nf < 8; ++nf)
        #pragma unroll
        for (int mf = 0; mf < 4; ++mf)
          acc[nf][mf] = (f32x4){0.f, 0.f, 0.f, 0.f};
    }

    const u16* A0 = Ah + ((2 * tt) & 3) * HSZ;
    const u16* B0 = Bh + ((2 * tt) & 3) * HSZ;
    const u16* A1 = Ah + ((2 * tt + 1) & 3) * HSZ;
    const u16* B1 = Bh + ((2 * tt + 1) & 3) * HSZ;
    const bool st = (tt < NTT - 1);

    bf16x8 b0, b1, b2, b3;

    // ---------- phase 0: k0, nf0-3 (8 reads) + stage A of half 2tt+2 ----------
    {
      bf16x8 a0 = *(const bf16x8*)&A0[aoff +    0];
      bf16x8 a1 = *(const bf16x8*)&A0[aoff +  512];
      bf16x8 a2 = *(const bf16x8*)&A0[aoff + 1024];
      bf16x8 a3 = *(const bf16x8*)&A0[aoff + 1536];
      b0 = *(const bf16x8*)&B0[boff +    0];
      b1 = *(const bf16x8*)&B0[boff +  512];
      b2 = *(const bf16x8*)&B0[boff + 1024];
      b3 = *(const bf16x8*)&B0[boff + 1536];
      if (st) STAGE_A_H(2 * tt + 2);
      __builtin_amdgcn_s_barrier();
      asm volatile("s_waitcnt lgkmcnt(0)" ::: "memory");
      __builtin_amdgcn_sched_barrier(0);
      __builtin_amdgcn_s_setprio(1);
      MFMA4(a0, 0) MFMA4(a1, 1) MFMA4(a2, 2) MFMA4(a3, 3)
      __builtin_amdgcn_s_setprio(0);
      __builtin_amdgcn_s_barrier();
    }
    // ---------- phase 1: k0, nf4-7 (4 reads, b reused) + stage B of 2tt+2 ------
    {
      bf16x8 a4 = *(const bf16x8*)&A0[aoff + 2048];
      bf16x8 a5 = *(const bf16x8*)&A0[aoff + 2560];
      bf16x8 a6 = *(const bf16x8*)&A0[aoff + 3072];
      bf16x8 a7 = *(const bf16x8*)&A0[aoff + 3584];
      if (st) STAGE_B_H(2 * tt + 2);
      __builtin_amdgcn_s_barrier();
      asm volatile("s_waitcnt lgkmcnt(0)" ::: "memory");
      __builtin_amdgcn_sched_barrier(0);
      __builtin_amdgcn_s_setprio(1);
      MFMA4(a4, 4) MFMA4(a5, 5) MFMA4(a6, 6) MFMA4(a7, 7)
      __builtin_amdgcn_s_setprio(0);
      if (st) { asm volatile("s_waitcnt vmcnt(4)" ::: "memory"); }
      else    { asm volatile("s_waitcnt vmcnt(0)" ::: "memory"); }
      __builtin_amdgcn_s_barrier();
    }
    // ---------- phase 2: k1, nf0-3 (8 reads) + stage A of half 2tt+3 ----------
    {
      bf16x8 a0 = *(const bf16x8*)&A1[aoff +    0];
      bf16x8 a1 = *(const bf16x8*)&A1[aoff +  512];
      bf16x8 a2 = *(const bf16x8*)&A1[aoff + 1024];
      bf16x8 a3 = *(const bf16x8*)&A1[aoff + 1536];
      b0 = *(const bf16x8*)&B1[boff +    0];
      b1 = *(const bf16x8*)&B1[boff +  512];
      b2 = *(const bf16x8*)&B1[boff + 1024];
      b3 = *(const bf16x8*)&B1[boff + 1536];
      if (st) STAGE_A_H(2 * tt + 3);
      __builtin_amdgcn_s_barrier();
      asm volatile("s_waitcnt lgkmcnt(0)" ::: "memory");
      __builtin_amdgcn_sched_barrier(0);
      __builtin_amdgcn_s_setprio(1);
      MFMA4(a0, 0) MFMA4(a1, 1) MFMA4(a2, 2) MFMA4(a3, 3)
      __builtin_amdgcn_s_setprio(0);
      __builtin_amdgcn_s_barrier();
    }
    // ---------- phase 3: k1, nf4-7 (4 reads) + stage B of 2tt+3 ---------------
    {
      bf16x8 a4 = *(const bf16x8*)&A1[aoff + 2048];
      bf16x8 a5 = *(const bf16x8*)&A1[aoff + 2560];
      bf16x8 a6 = *(const bf16x8*)&A1[aoff + 3072];
      bf16x8 a7 = *(const bf16x8*)&A1[aoff + 3584];
      if (st) STAGE_B_H(2 * tt + 3);
      __builtin_amdgcn_s_barrier();
      asm volatile("s_waitcnt lgkmcnt(0)" ::: "memory");
      __builtin_amdgcn_sched_barrier(0);
      __builtin_amdgcn_s_setprio(1);
      MFMA4(a4, 4) MFMA4(a5, 5) MFMA4(a6, 6) MFMA4(a7, 7)
      __builtin_amdgcn_s_setprio(0);
      if (st) { asm volatile("s_waitcnt vmcnt(4)" ::: "memory"); }
      __builtin_amdgcn_s_barrier();
    }

    // ---------- per-n-tile register epilogue (regs + global reads only) -------
    if ((tt & 7) == 7) {
      const int nbase = ncoff + (tt >> 3) * BN + wn * 128 + g * 4;
      #pragma unroll
      for (int nf = 0; nf < 8; ++nf) {
        const float4 q = *(const float4*)&nm[nbase + nf * 16];
        #pragma unroll
        for (int mf = 0; mf < 4; ++mf) {
          float v0 = fmaf(-2.0f, acc[nf][mf][0], q.x);
          float v1 = fmaf(-2.0f, acc[nf][mf][1], q.y);
          float v2 = fmaf(-2.0f, acc[nf][mf][2], q.z);
          float v3 = fmaf(-2.0f, acc[nf][mf][3], q.w);
          float bm = fminf(fminf(v0, v1), fminf(v2, v3));
          if (bm < T[mf]) {
            topk_update(v0, best[mf]);
            topk_update(v1, best[mf]);
            topk_update(v2, best[mf]);
            topk_update(v3, best[mf]);
            T[mf] = best[mf][TOPK - 1];
          }
        }
      }
      #pragma unroll
      for (int mf = 0; mf < 4; ++mf) {
        float tb = best[mf][TOPK - 1];
        tb = fminf(tb, __shfl_xor(tb, 16, 64));
        tb = fminf(tb, __shfl_xor(tb, 32, 64));
        T[mf] = tb;
      }
    }
  }

  // ---- butterfly merge across the 4 lane-groups sharing each m-col ----
  #pragma unroll
  for (int mf = 0; mf < 4; ++mf) {
    float tmp[TOPK];
    #pragma unroll
    for (int q = 0; q < TOPK; ++q) tmp[q] = __shfl_xor(best[mf][q], 16, 64);
    #pragma unroll
    for (int q = 0; q < TOPK; ++q) topk_update(tmp[q], best[mf]);
    #pragma unroll
    for (int q = 0; q < TOPK; ++q) tmp[q] = __shfl_xor(best[mf][q], 32, 64);
    #pragma unroll
    for (int q = 0; q < TOPK; ++q) topk_update(tmp[q], best[mf]);
  }

  // ---- cross-wave merge: wn=1 stashes (LDS reused), wn=0 merges + writes ----
  float* smerge = (float*)sm;          // 256*9*4 = 9216 B
  __syncthreads();
  if (wn == 1 && g == 0) {
    #pragma unroll
    for (int mf = 0; mf < 4; ++mf)
      #pragma unroll
      for (int q = 0; q < TOPK; ++q)
        smerge[(wm * 64 + mf * 16 + r16) * TOPK + q] = best[mf][q];
  }
  __syncthreads();
  if (wn == 0 && g == 0) {
    #pragma unroll
    for (int mf = 0; mf < 4; ++mf) {
      const float* p = &smerge[(wm * 64 + mf * 16 + r16) * TOPK];
      #pragma unroll
      for (int q = 0; q < TOPK; ++q) topk_update(p[q], best[mf]);
      const int m = m0 + wm * 64 + mf * 16 + r16;
      float* dst = &partial[((size_t)blockIdx.y * M_ROWS + m) * TOPK];
      #pragma unroll
      for (int q = 0; q < TOPK; ++q) dst[q] = best[mf][q];
    }
  }
}

// ---- Kernel 3: merge 8 partial lists/row (parallel, R9 structure) ----
__global__ __launch_bounds__(64) void merge_kernel(
    const float* __restrict__ partial, const float* __restrict__ nf,
    float* __restrict__ final9, float* __restrict__ out_pix)
{
  const int l   = threadIdx.x;            // 0..63
  const int row = blockIdx.x * 16 + (l & 15);
  const int q4  = l >> 4;                 // chunk quarter 0..3 (2 chunks each)
  float best[TOPK];
  #pragma unroll
  for (int i = 0; i < TOPK; ++i) best[i] = 3.4e38f;
  #pragma unroll
  for (int s = 0; s < 2; ++s) {
    const float* p = &partial[((size_t)(q4 * 2 + s) * M_ROWS + row) * TOPK];
    #pragma unroll
    for (int i = 0; i < TOPK; ++i) {
      float pv = p[i];
      if (pv >= best[TOPK - 1]) break;    // chunk lists are sorted ascending
      topk_update(pv, best);
    }
  }
  {
    float tmp[TOPK];
    #pragma unroll
    for (int q = 0; q < TOPK; ++q) tmp[q] = __shfl_xor(best[q], 32, 64);
    #pragma unroll
    for (int q = 0; q < TOPK; ++q) topk_update(tmp[q], best);
    #pragma unroll
    for (int q = 0; q < TOPK; ++q) tmp[q] = __shfl_xor(best[q], 16, 64);
    #pragma unroll
    for (int q = 0; q < TOPK; ++q) topk_update(tmp[q], best);
  }
  if (q4 == 0) {
    float nfr = nf[row];
    float d[TOPK];
    #pragma unroll
    for (int i = 0; i < TOPK; ++i) d[i] = sqrtf(fmaxf(best[i] + nfr, 0.0f));
    out_pix[row] = d[0];
    #pragma unroll
    for (int i = 0; i < TOPK; ++i) final9[(size_t)row * TOPK + i] = d[i];
  }
}

// ---- Kernel 4: per-image argmax (first-max) + softmax score ----
__global__ __launch_bounds__(256) void img_kernel(
    const float* __restrict__ out_pix, const float* __restrict__ final9,
    const int* __restrict__ bptr, float* __restrict__ out_img)
{
  int img = blockIdx.x, t = threadIdx.x;
  float bv = -1.0f; int bi = 0;
  for (int p = t; p < 1024; p += 256) {
    float v = out_pix[img * 1024 + p];
    if (v > bv) { bv = v; bi = p; }
  }
  __shared__ float sv[256];
  __shared__ int   si[256];
  sv[t] = bv; si[t] = bi;
  __syncthreads();
  for (int off = 128; off > 0; off >>= 1) {
    if (t < off) {
      float v2 = sv[t + off]; int i2 = si[t + off];
      if (v2 > sv[t] || (v2 == sv[t] && i2 < si[t])) { sv[t] = v2; si[t] = i2; }
    }
    __syncthreads();
  }
  if (t == 0) {
    int row = img * 1024 + si[0];
    int b = bptr[0];
    float s0 = final9[(size_t)row * TOPK + 0];
    float score = s0;
    if (b > 1) {
      int bb = b < TOPK ? b : TOPK;
      float mx = s0;
      for (int i = 1; i < bb; ++i) mx = fmaxf(mx, final9[(size_t)row * TOPK + i]);
      float den = 0.0f;
      for (int i = 0; i < bb; ++i) den += expf(final9[(size_t)row * TOPK + i] - mx);
      score = s0 * (1.0f - expf(s0 - mx) / den);
    }
    out_img[img] = score;
  }
}

extern "C" void kernel_launch(void* const* d_in, const int* in_sizes, int n_in,
                              void* d_out, int out_size, void* d_ws, size_t ws_size,
                              hipStream_t stream) {
  const float* fv   = (const float*)d_in[0];
  const float* mb   = (const float*)d_in[1];
  const int*   bptr = (const int*)d_in[2];
  float* out = (float*)d_out;

  char* ws = (char*)d_ws;
  u16*   fvb     = (u16*)ws;                       // 8388608 B
  u16*   mbb     = (u16*)(ws + 8388608);           // 16777216 B
  float* nf      = (float*)(ws + 25165824);        // 32768 B
  float* nm      = (float*)(ws + 25198592);        // 65536 B (plain order)
  float* partial = (float*)(ws + 25264128);        // 8*8192*9*4 = 2359296 B
  float* final9  = (float*)(ws + 27623424);        // 294912 B (end ~27.9 MB)

  hipLaunchKernelGGL(prep_kernel, dim3((M_ROWS + N_ROWS) / 4), dim3(256), 0, stream,
                     fv, mb, fvb, mbb, nf, nm);
  hipLaunchKernelGGL(gemm_topk_kernel, dim3(M_ROWS / BM, NCHUNKS), dim3(512),
                     131072, stream, fvb, mbb, nm, partial);
  hipLaunchKernelGGL(merge_kernel, dim3(M_ROWS / 16), dim3(64), 0, stream,
                     partial, nf, final9, out);
  hipLaunchKernelGGL(img_kernel, dim3(8), dim3(256), 0, stream,
                     out, final9, bptr, out + M_ROWS);
}